// Round 2
// baseline (1290.007 us; speedup 1.0000x reference)
//
#include <hip/hip_runtime.h>
#include <math.h>

#define TAU_INV 1.25f
#define LAMBDA 0.5f
#define NR 4096
#define HD 512

// ---------------- GEMM NT: C[M,N] = A[M,K] @ B[N,K]^T + bias, optional ELU ----------------
template <bool DO_ELU>
__global__ __launch_bounds__(256) void gemm_nt(const float* __restrict__ A,
                                               const float* __restrict__ B,
                                               const float* __restrict__ bias,
                                               float* __restrict__ C,
                                               int M, int N, int K) {
  __shared__ float As[16][64];
  __shared__ float Bs[16][64];
  const int tid = threadIdx.x;
  const int tx = tid & 15, ty = tid >> 4;
  const int rowbase = blockIdx.y * 64;
  const int colbase = blockIdx.x * 64;
  const int lr = tid >> 2;          // 0..63
  const int lk = (tid & 3) << 2;    // 0,4,8,12
  const float* Ap = A + (size_t)(rowbase + lr) * K + lk;
  const float* Bp = B + (size_t)(colbase + lr) * K + lk;
  float acc[4][4] = {};
  for (int kb = 0; kb < K; kb += 16) {
    float4 av = *(const float4*)(Ap + kb);
    float4 bv = *(const float4*)(Bp + kb);
    __syncthreads();
    As[lk + 0][lr] = av.x; As[lk + 1][lr] = av.y; As[lk + 2][lr] = av.z; As[lk + 3][lr] = av.w;
    Bs[lk + 0][lr] = bv.x; Bs[lk + 1][lr] = bv.y; Bs[lk + 2][lr] = bv.z; Bs[lk + 3][lr] = bv.w;
    __syncthreads();
#pragma unroll
    for (int k = 0; k < 16; ++k) {
      float a0 = As[k][ty * 4 + 0], a1 = As[k][ty * 4 + 1], a2 = As[k][ty * 4 + 2], a3 = As[k][ty * 4 + 3];
      float b0 = Bs[k][tx * 4 + 0], b1 = Bs[k][tx * 4 + 1], b2 = Bs[k][tx * 4 + 2], b3 = Bs[k][tx * 4 + 3];
      acc[0][0] += a0 * b0; acc[0][1] += a0 * b1; acc[0][2] += a0 * b2; acc[0][3] += a0 * b3;
      acc[1][0] += a1 * b0; acc[1][1] += a1 * b1; acc[1][2] += a1 * b2; acc[1][3] += a1 * b3;
      acc[2][0] += a2 * b0; acc[2][1] += a2 * b1; acc[2][2] += a2 * b2; acc[2][3] += a2 * b3;
      acc[3][0] += a3 * b0; acc[3][1] += a3 * b1; acc[3][2] += a3 * b2; acc[3][3] += a3 * b3;
    }
  }
  float4 bb = *(const float4*)(bias + colbase + tx * 4);
#pragma unroll
  for (int r = 0; r < 4; ++r) {
    float4 v;
    v.x = acc[r][0] + bb.x; v.y = acc[r][1] + bb.y; v.z = acc[r][2] + bb.z; v.w = acc[r][3] + bb.w;
    if (DO_ELU) {
      v.x = v.x > 0.f ? v.x : expm1f(v.x);
      v.y = v.y > 0.f ? v.y : expm1f(v.y);
      v.z = v.z > 0.f ? v.z : expm1f(v.z);
      v.w = v.w > 0.f ? v.w : expm1f(v.w);
    }
    *(float4*)(C + (size_t)(rowbase + ty * 4 + r) * N + colbase + tx * 4) = v;
  }
}

// ---------------- row L2 norms: one wave (64 lanes) per row of [rows,512] ----------------
__global__ __launch_bounds__(256) void rownorm(const float* __restrict__ Z,
                                               float* __restrict__ out, int rows) {
  int wid = blockIdx.x * 4 + (threadIdx.x >> 6);
  int lane = threadIdx.x & 63;
  if (wid >= rows) return;
  const float4* z = (const float4*)(Z + (size_t)wid * HD);
  float s = 0.f;
#pragma unroll
  for (int t = 0; t < 2; ++t) {
    float4 v = z[lane * 2 + t];
    s += v.x * v.x + v.y * v.y + v.z * v.z + v.w * v.w;
  }
#pragma unroll
  for (int off = 1; off < 64; off <<= 1) s += __shfl_xor(s, off);
  if (lane == 0) out[wid] = sqrtf(s);
}

// ---------------- fused similarity: S=PA@PB^T, m=exp(cos/tau), accumulate row/col sums ----------------
__global__ __launch_bounds__(256) void sim_fused(const float* __restrict__ PA,
                                                 const float* __restrict__ PB,
                                                 const float* __restrict__ nm,
                                                 const float* __restrict__ ns,
                                                 const float* __restrict__ pos,
                                                 float* __restrict__ accRowSum,
                                                 float* __restrict__ accRowPos,
                                                 float* __restrict__ accColSum,
                                                 float* __restrict__ accColPos) {
  __shared__ float As[16][64];
  __shared__ float Bs[16][64];
  __shared__ float red[64][16];
  const int tid = threadIdx.x;
  const int tx = tid & 15, ty = tid >> 4;
  const int rowbase = blockIdx.y * 64;
  const int colbase = blockIdx.x * 64;
  const int lr = tid >> 2;
  const int lk = (tid & 3) << 2;
  const float* Ap = PA + (size_t)(rowbase + lr) * HD + lk;
  const float* Bp = PB + (size_t)(colbase + lr) * HD + lk;
  float acc[4][4] = {};
  for (int kb = 0; kb < HD; kb += 16) {
    float4 av = *(const float4*)(Ap + kb);
    float4 bv = *(const float4*)(Bp + kb);
    __syncthreads();
    As[lk + 0][lr] = av.x; As[lk + 1][lr] = av.y; As[lk + 2][lr] = av.z; As[lk + 3][lr] = av.w;
    Bs[lk + 0][lr] = bv.x; Bs[lk + 1][lr] = bv.y; Bs[lk + 2][lr] = bv.z; Bs[lk + 3][lr] = bv.w;
    __syncthreads();
#pragma unroll
    for (int k = 0; k < 16; ++k) {
      float a0 = As[k][ty * 4 + 0], a1 = As[k][ty * 4 + 1], a2 = As[k][ty * 4 + 2], a3 = As[k][ty * 4 + 3];
      float b0 = Bs[k][tx * 4 + 0], b1 = Bs[k][tx * 4 + 1], b2 = Bs[k][tx * 4 + 2], b3 = Bs[k][tx * 4 + 3];
      acc[0][0] += a0 * b0; acc[0][1] += a0 * b1; acc[0][2] += a0 * b2; acc[0][3] += a0 * b3;
      acc[1][0] += a1 * b0; acc[1][1] += a1 * b1; acc[1][2] += a1 * b2; acc[1][3] += a1 * b3;
      acc[2][0] += a2 * b0; acc[2][1] += a2 * b1; acc[2][2] += a2 * b2; acc[2][3] += a2 * b3;
      acc[3][0] += a3 * b0; acc[3][1] += a3 * b1; acc[3][2] += a3 * b2; acc[3][3] += a3 * b3;
    }
  }
  // epilogue: m = exp(acc / (nm*ns) * (1/tau))
  float nmv[4], nsv[4];
#pragma unroll
  for (int r = 0; r < 4; ++r) nmv[r] = nm[rowbase + ty * 4 + r];
#pragma unroll
  for (int c = 0; c < 4; ++c) nsv[c] = ns[colbase + tx * 4 + c];
  float mm[4][4];
#pragma unroll
  for (int r = 0; r < 4; ++r)
#pragma unroll
    for (int c = 0; c < 4; ++c)
      mm[r][c] = expf(acc[r][c] / (nmv[r] * nsv[c]) * TAU_INV);

  float rs[4], rp[4], cs[4] = {}, cp[4];
#pragma unroll
  for (int r = 0; r < 4; ++r) {
    float4 p4 = *(const float4*)(pos + (size_t)(rowbase + ty * 4 + r) * NR + colbase + tx * 4);
    rs[r] = mm[r][0] + mm[r][1] + mm[r][2] + mm[r][3];
    rp[r] = mm[r][0] * p4.x + mm[r][1] * p4.y + mm[r][2] * p4.z + mm[r][3] * p4.w;
    cs[0] += mm[r][0]; cs[1] += mm[r][1]; cs[2] += mm[r][2]; cs[3] += mm[r][3];
  }
#pragma unroll
  for (int c = 0; c < 4; ++c) {
    float4 p4 = *(const float4*)(pos + (size_t)(colbase + tx * 4 + c) * NR + rowbase + ty * 4);
    cp[c] = mm[0][c] * p4.x + mm[1][c] * p4.y + mm[2][c] * p4.z + mm[3][c] * p4.w;
  }

  // block reductions (row quantities: reduce across tx; col quantities: across ty)
  __syncthreads();
#pragma unroll
  for (int r = 0; r < 4; ++r) red[ty * 4 + r][tx] = rs[r];
  __syncthreads();
  if (tid < 64) {
    float s = 0.f;
#pragma unroll
    for (int t = 0; t < 16; ++t) s += red[tid][t];
    atomicAdd(&accRowSum[rowbase + tid], s);
  }
  __syncthreads();
#pragma unroll
  for (int r = 0; r < 4; ++r) red[ty * 4 + r][tx] = rp[r];
  __syncthreads();
  if (tid < 64) {
    float s = 0.f;
#pragma unroll
    for (int t = 0; t < 16; ++t) s += red[tid][t];
    atomicAdd(&accRowPos[rowbase + tid], s);
  }
  __syncthreads();
#pragma unroll
  for (int c = 0; c < 4; ++c) red[tx * 4 + c][ty] = cs[c];
  __syncthreads();
  if (tid < 64) {
    float s = 0.f;
#pragma unroll
    for (int t = 0; t < 16; ++t) s += red[tid][t];
    atomicAdd(&accColSum[colbase + tid], s);
  }
  __syncthreads();
#pragma unroll
  for (int c = 0; c < 4; ++c) red[tx * 4 + c][ty] = cp[c];
  __syncthreads();
  if (tid < 64) {
    float s = 0.f;
#pragma unroll
    for (int t = 0; t < 16; ++t) s += red[tid][t];
    atomicAdd(&accColPos[colbase + tid], s);
  }
}

// ---------------- pair dot + log-sigmoid: one wave per pair ----------------
__global__ __launch_bounds__(256) void pair_logsig(const float* __restrict__ zm1,
                                                   const float* __restrict__ zs1,
                                                   const float* __restrict__ zm2,
                                                   const float* __restrict__ zs2,
                                                   const int* __restrict__ pi,
                                                   const int* __restrict__ pj,
                                                   const int* __restrict__ ni,
                                                   const int* __restrict__ nj,
                                                   int P, float* __restrict__ lsig) {
  int wid = blockIdx.x * 4 + (threadIdx.x >> 6);
  int lane = threadIdx.x & 63;
  if (wid >= 2 * P) return;
  bool isneg = wid >= P;
  int p = isneg ? wid - P : wid;
  int i = isneg ? ni[p] : pi[p];
  int j = isneg ? nj[p] : pj[p];
  const float4* am = (const float4*)(zm1 + (size_t)i * HD);
  const float4* as_ = (const float4*)(zs1 + (size_t)i * HD);
  const float4* bm = (const float4*)(zm2 + (size_t)j * HD);
  const float4* bs_ = (const float4*)(zs2 + (size_t)j * HD);
  float s = 0.f;
#pragma unroll
  for (int t = 0; t < 2; ++t) {
    int k = lane * 2 + t;
    float4 x = am[k], xs = as_[k], y = bm[k], ys = bs_[k];
    s += (x.x + xs.x) * (y.x + ys.x) + (x.y + xs.y) * (y.y + ys.y) +
         (x.z + xs.z) * (y.z + ys.z) + (x.w + xs.w) * (y.w + ys.w);
  }
#pragma unroll
  for (int off = 1; off < 64; off <<= 1) s += __shfl_xor(s, off);
  if (lane == 0) {
    float ip = isneg ? -s : s;
    float v = fminf(ip, 0.f) - log1pf(expf(-fabsf(ip)));
    lsig[wid] = v;
  }
}

// ---------------- final reduction + combine ----------------
__global__ __launch_bounds__(256) void finalize(const float* __restrict__ acc,  // [8][4096]: l*4+{rs,rp,cs,cp}
                                                const float* __restrict__ lsig, // [2P]
                                                int P, float* __restrict__ out) {
  int tid = threadIdx.x;
  __shared__ float red[256];
  float local[6] = {0.f, 0.f, 0.f, 0.f, 0.f, 0.f};
  for (int l = 0; l < 2; ++l) {
    const float* rs = acc + (size_t)(l * 4 + 0) * NR;
    const float* rp = acc + (size_t)(l * 4 + 1) * NR;
    const float* cs = acc + (size_t)(l * 4 + 2) * NR;
    const float* cp = acc + (size_t)(l * 4 + 3) * NR;
    for (int i = tid; i < NR; i += 256) {
      local[l * 2 + 0] += logf(rp[i] / (rs[i] + 1e-8f));
      local[l * 2 + 1] += logf(cp[i] / (cs[i] + 1e-8f));
    }
  }
  for (int i = tid; i < P; i += 256) local[4] += lsig[i];
  for (int i = tid; i < P; i += 256) local[5] += lsig[P + i];
  float tot[6];
  for (int q = 0; q < 6; ++q) {
    red[tid] = local[q];
    __syncthreads();
    for (int s = 128; s > 0; s >>= 1) {
      if (tid < s) red[tid] += red[tid + s];
      __syncthreads();
    }
    tot[q] = red[0];
    __syncthreads();
  }
  if (tid == 0) {
    float lori_mp1 = -tot[0] / (float)NR, lori_sc1 = -tot[1] / (float)NR;
    float lori_mp2 = -tot[2] / (float)NR, lori_sc2 = -tot[3] / (float)NR;
    float loss1 = LAMBDA * lori_mp1 + (1.f - LAMBDA) * lori_sc1;
    float loss2 = LAMBDA * lori_mp2 + (1.f - LAMBDA) * lori_sc2;
    float loss_main = -(tot[4] / (float)P) + (tot[5] / (float)P);
    out[0] = loss_main + loss1 + loss2;
  }
}

extern "C" void kernel_launch(void* const* d_in, const int* in_sizes, int n_in,
                              void* d_out, int out_size, void* d_ws, size_t ws_size,
                              hipStream_t stream) {
  const float* z_mp1 = (const float*)d_in[0];
  const float* z_sc1 = (const float*)d_in[1];
  const float* pos1 = (const float*)d_in[2];
  const float* z_mp2 = (const float*)d_in[3];
  const float* z_sc2 = (const float*)d_in[4];
  const float* pos2 = (const float*)d_in[5];
  const float* W1 = (const float*)d_in[6];
  const float* b1 = (const float*)d_in[7];
  const float* W2 = (const float*)d_in[8];
  const float* b2 = (const float*)d_in[9];
  const int* pi = (const int*)d_in[10];
  const int* pj = (const int*)d_in[11];
  const int* ni = (const int*)d_in[12];
  const int* nj = (const int*)d_in[13];
  const int P = in_sizes[10];

  float* ws = (float*)d_ws;
  float* ACC = ws;                          // 16*4096 (only 8*4096 used, zeroed all)
  float* NORMS = ws + 16 * 4096;            // 4*4096
  float* PAbuf = ws + 16 * 4096 + 4 * 4096 + 16;  // 16B-aligned
  float* PBbuf = PAbuf + (size_t)NR * HD;
  float* HB = PBbuf + (size_t)NR * HD;
  float* LSIG = HB + (size_t)NR * HD;       // 2P floats

  hipMemsetAsync(ACC, 0, (16 * 4096) * sizeof(float), stream);

  {
    int nwaves = 2 * P;
    dim3 pg((nwaves + 3) / 4);
    pair_logsig<<<pg, 256, 0, stream>>>(z_mp1, z_sc1, z_mp2, z_sc2, pi, pj, ni, nj, P, LSIG);
  }

  dim3 gP(HD / 64, NR / 64);  // (8, 64)
  dim3 gS(NR / 64, NR / 64);  // (64, 64)
  for (int l = 0; l < 2; ++l) {
    const float* zm = l ? z_mp2 : z_mp1;
    const float* zs = l ? z_sc2 : z_sc1;
    const float* pos = l ? pos2 : pos1;
    gemm_nt<true><<<gP, 256, 0, stream>>>(zm, W1, b1, HB, NR, HD, HD);
    gemm_nt<false><<<gP, 256, 0, stream>>>(HB, W2, b2, PAbuf, NR, HD, HD);
    gemm_nt<true><<<gP, 256, 0, stream>>>(zs, W1, b1, HB, NR, HD, HD);
    gemm_nt<false><<<gP, 256, 0, stream>>>(HB, W2, b2, PBbuf, NR, HD, HD);
    rownorm<<<dim3(1024), 256, 0, stream>>>(PAbuf, NORMS + l * 2 * 4096, NR);
    rownorm<<<dim3(1024), 256, 0, stream>>>(PBbuf, NORMS + l * 2 * 4096 + 4096, NR);
    sim_fused<<<gS, 256, 0, stream>>>(PAbuf, PBbuf, NORMS + l * 2 * 4096, NORMS + l * 2 * 4096 + 4096, pos,
                                      ACC + (size_t)(l * 4 + 0) * 4096, ACC + (size_t)(l * 4 + 1) * 4096,
                                      ACC + (size_t)(l * 4 + 2) * 4096, ACC + (size_t)(l * 4 + 3) * 4096);
  }
  finalize<<<1, 256, 0, stream>>>(ACC, LSIG, P, (float*)d_out);
}

// Round 4
// 558.772 us; speedup vs baseline: 2.3086x; 2.3086x over previous
//
#include <hip/hip_runtime.h>
#include <math.h>

#define TAU_INV 1.25f
#define LAMBDA 0.5f
#define NR 4096
#define HD 512

typedef __attribute__((ext_vector_type(8))) short short8;
typedef __attribute__((ext_vector_type(4))) float f32x4;
typedef __attribute__((ext_vector_type(4))) unsigned short ushort4v;

static __device__ __forceinline__ unsigned short f2bf(float f) {
  unsigned int u = __float_as_uint(f);
  u += 0x7fff + ((u >> 16) & 1);   // RNE
  return (unsigned short)(u >> 16);
}
static __device__ __forceinline__ float bf2f(unsigned short s) {
  return __uint_as_float(((unsigned int)s) << 16);
}

// ---------------- fp32 -> bf16 cast (vectorized) ----------------
__global__ __launch_bounds__(256) void cast_bf16(const float* __restrict__ src,
                                                 unsigned short* __restrict__ dst, int n4) {
  int i = blockIdx.x * 256 + threadIdx.x;
  if (i < n4) {
    float4 v = ((const float4*)src)[i];
    ushort4v o;
    o.x = f2bf(v.x); o.y = f2bf(v.y); o.z = f2bf(v.z); o.w = f2bf(v.w);
    ((ushort4v*)dst)[i] = o;
  }
}

// ---------------- zsum = a + b (fp32, for pair loss) ----------------
__global__ __launch_bounds__(256) void addz(const float* __restrict__ a,
                                            const float* __restrict__ b,
                                            float* __restrict__ o, int n4) {
  int i = blockIdx.x * 256 + threadIdx.x;
  if (i < n4) {
    float4 x = ((const float4*)a)[i], y = ((const float4*)b)[i];
    float4 r; r.x = x.x + y.x; r.y = x.y + y.y; r.z = x.z + y.z; r.w = x.w + y.w;
    ((float4*)o)[i] = r;
  }
}

// ============ MFMA GEMM core macros (128x128 tile, BK=64, XOR-swizzled LDS) ============
// LDS slot (row, c16) holds global element (row, c16 ^ ((row&7)<<4)); reads re-apply the XOR.

#define GEMM_STAGE(Aptr, Bptr, rb, cb_, kb)                                                     \
  {                                                                                             \
    _Pragma("unroll") for (int q = 0; q < 4; ++q) {                                             \
      int r0 = q * 32 + w * 8;                                                                  \
      const char* sa = (const char*)(Aptr) + ((size_t)((rb) + r0 + lrow) << 10) + (kb)*128 + scb;\
      const char* sb = (const char*)(Bptr) + ((size_t)((cb_) + r0 + lrow) << 10) + (kb)*128 + scb;\
      __builtin_amdgcn_global_load_lds((const __attribute__((address_space(1))) unsigned int*)sa,\
          (__attribute__((address_space(3))) unsigned int*)(void*)((char*)As + r0 * 128), 16, 0, 0);\
      __builtin_amdgcn_global_load_lds((const __attribute__((address_space(1))) unsigned int*)sb,\
          (__attribute__((address_space(3))) unsigned int*)(void*)((char*)Bs + r0 * 128), 16, 0, 0);\
    }                                                                                           \
  }

#define GEMM_COMPUTE()                                                                          \
  {                                                                                             \
    _Pragma("unroll") for (int kk = 0; kk < 2; ++kk) {                                          \
      short8 av[4], bv[4];                                                                      \
      _Pragma("unroll") for (int mf = 0; mf < 4; ++mf) {                                        \
        int row = wr * 64 + mf * 16 + (l & 15);                                                 \
        int kbyte = ((kk * 64) + ((l >> 4) * 16)) ^ ((l & 7) << 4);                             \
        av[mf] = *(const short8*)((const char*)As + row * 128 + kbyte);                         \
      }                                                                                         \
      _Pragma("unroll") for (int nf = 0; nf < 4; ++nf) {                                        \
        int row = wc * 64 + nf * 16 + (l & 15);                                                 \
        int kbyte = ((kk * 64) + ((l >> 4) * 16)) ^ ((l & 7) << 4);                             \
        bv[nf] = *(const short8*)((const char*)Bs + row * 128 + kbyte);                         \
      }                                                                                         \
      _Pragma("unroll") for (int mf = 0; mf < 4; ++mf)                                          \
        _Pragma("unroll") for (int nf = 0; nf < 4; ++nf)                                        \
          acc[mf][nf] = __builtin_amdgcn_mfma_f32_16x16x32_bf16(av[mf], bv[nf], acc[mf][nf], 0, 0, 0);\
    }                                                                                           \
  }

// ---------------- proj GEMM: C = A @ W^T + bias (optional ELU), bf16 in/out, 2 streams ----------------
template <bool DO_ELU>
__global__ __launch_bounds__(256) void proj_mfma(const unsigned short* __restrict__ A0,
                                                 const unsigned short* __restrict__ A1,
                                                 const unsigned short* __restrict__ B,
                                                 const float* __restrict__ bias,
                                                 unsigned short* __restrict__ C0,
                                                 unsigned short* __restrict__ C1) {
  __shared__ unsigned short As[128 * 64];
  __shared__ unsigned short Bs[128 * 64];
  const int tid = threadIdx.x;
  const int l = tid & 63, w = tid >> 6;
  const int wr = w >> 1, wc = w & 1;
  const int stream_id = blockIdx.y >> 5;
  const int rowbase = (blockIdx.y & 31) * 128;
  const int colbase = blockIdx.x * 128;
  const unsigned short* A = stream_id ? A1 : A0;
  unsigned short* C = stream_id ? C1 : C0;
  const int lrow = l >> 3;
  const int scb = ((l & 7) ^ lrow) << 4;

  f32x4 acc[4][4];
#pragma unroll
  for (int i = 0; i < 4; ++i)
#pragma unroll
    for (int j = 0; j < 4; ++j) acc[i][j] = (f32x4){0.f, 0.f, 0.f, 0.f};

  for (int kb = 0; kb < 8; ++kb) {
    GEMM_STAGE(A, B, rowbase, colbase, kb);
    __syncthreads();
    GEMM_COMPUTE();
    __syncthreads();
  }

  const int cq = l >> 4, cn = l & 15;
#pragma unroll
  for (int mf = 0; mf < 4; ++mf) {
#pragma unroll
    for (int nf = 0; nf < 4; ++nf) {
      int col = colbase + wc * 64 + nf * 16 + cn;
      float bb = bias[col];
#pragma unroll
      for (int j = 0; j < 4; ++j) {
        int row = rowbase + wr * 64 + mf * 16 + cq * 4 + j;
        float v = acc[mf][nf][j] + bb;
        if (DO_ELU) v = v > 0.f ? v : expm1f(v);
        C[(size_t)row * HD + col] = f2bf(v);
      }
    }
  }
}

// ---------------- row inv-norms from bf16 [rows,512] ----------------
__global__ __launch_bounds__(256) void rownorm_bf(const unsigned short* __restrict__ Z,
                                                  float* __restrict__ inv, int rows) {
  int wid = blockIdx.x * 4 + (threadIdx.x >> 6);
  int lane = threadIdx.x & 63;
  if (wid >= rows) return;
  short8 v = ((const short8*)(Z + (size_t)wid * HD))[lane];
  float s = 0.f;
#pragma unroll
  for (int j = 0; j < 8; ++j) {
    float f = bf2f((unsigned short)v[j]);
    s += f * f;
  }
#pragma unroll
  for (int off = 1; off < 64; off <<= 1) s += __shfl_xor(s, off);
  if (lane == 0) inv[wid] = 1.f / sqrtf(s);
}

// ---------------- fused similarity (MFMA) + exp + row/col pos-weighted reductions ----------------
__global__ __launch_bounds__(256) void sim_mfma(const unsigned short* __restrict__ PA,
                                                const unsigned short* __restrict__ PB,
                                                const float* __restrict__ invA,
                                                const float* __restrict__ invB,
                                                const float* __restrict__ pos,
                                                float* __restrict__ accRS,
                                                float* __restrict__ accRP,
                                                float* __restrict__ accCS,
                                                float* __restrict__ accCP) {
  __shared__ unsigned short As[128 * 64];
  __shared__ unsigned short Bs[128 * 64];
  const int tid = threadIdx.x;
  const int l = tid & 63, w = tid >> 6;
  const int wr = w >> 1, wc = w & 1;
  const int rowbase = blockIdx.y * 128;
  const int colbase = blockIdx.x * 128;
  const int lrow = l >> 3;
  const int scb = ((l & 7) ^ lrow) << 4;

  f32x4 acc[4][4];
#pragma unroll
  for (int i = 0; i < 4; ++i)
#pragma unroll
    for (int j = 0; j < 4; ++j) acc[i][j] = (f32x4){0.f, 0.f, 0.f, 0.f};

  for (int kb = 0; kb < 8; ++kb) {
    GEMM_STAGE(PA, PB, rowbase, colbase, kb);
    __syncthreads();
    GEMM_COMPUTE();
    __syncthreads();
  }

  const int cq = l >> 4, cn = l & 15;
  // scales
  float sr[4][4], sc[4];
#pragma unroll
  for (int mf = 0; mf < 4; ++mf) {
    float4 iv = *(const float4*)(invA + rowbase + wr * 64 + mf * 16 + cq * 4);
    sr[mf][0] = iv.x * TAU_INV; sr[mf][1] = iv.y * TAU_INV;
    sr[mf][2] = iv.z * TAU_INV; sr[mf][3] = iv.w * TAU_INV;
  }
#pragma unroll
  for (int nf = 0; nf < 4; ++nf) sc[nf] = invB[colbase + wc * 64 + nf * 16 + cn];

  // m = exp(dot * invA * invB / tau), in place
#pragma unroll
  for (int mf = 0; mf < 4; ++mf)
#pragma unroll
    for (int nf = 0; nf < 4; ++nf)
#pragma unroll
      for (int j = 0; j < 4; ++j)
        acc[mf][nf][j] = expf(acc[mf][nf][j] * sr[mf][j] * sc[nf]);

  // row sums + pos-weighted row sums
#pragma unroll
  for (int mf = 0; mf < 4; ++mf) {
    float rs[4] = {0.f, 0.f, 0.f, 0.f}, rp[4] = {0.f, 0.f, 0.f, 0.f};
#pragma unroll
    for (int nf = 0; nf < 4; ++nf) {
      int col = colbase + wc * 64 + nf * 16 + cn;
#pragma unroll
      for (int j = 0; j < 4; ++j) {
        float m = acc[mf][nf][j];
        rs[j] += m;
        float p = pos[(size_t)(rowbase + wr * 64 + mf * 16 + cq * 4 + j) * NR + col];
        rp[j] += m * p;
      }
    }
#pragma unroll
    for (int off = 1; off < 16; off <<= 1) {
#pragma unroll
      for (int j = 0; j < 4; ++j) { rs[j] += __shfl_xor(rs[j], off); rp[j] += __shfl_xor(rp[j], off); }
    }
    if (cn == 0) {
#pragma unroll
      for (int j = 0; j < 4; ++j) {
        int row = rowbase + wr * 64 + mf * 16 + cq * 4 + j;
        atomicAdd(&accRS[row], rs[j]);
        atomicAdd(&accRP[row], rp[j]);
      }
    }
  }

  // col sums + pos^T-weighted col sums
  float cs[4] = {0.f, 0.f, 0.f, 0.f}, cp[4] = {0.f, 0.f, 0.f, 0.f};
#pragma unroll
  for (int nf = 0; nf < 4; ++nf) {
    int col = colbase + wc * 64 + nf * 16 + cn;
#pragma unroll
    for (int mf = 0; mf < 4; ++mf) {
      float4 pT = *(const float4*)(pos + (size_t)col * NR + rowbase + wr * 64 + mf * 16 + cq * 4);
      float pj[4] = {pT.x, pT.y, pT.z, pT.w};
#pragma unroll
      for (int j = 0; j < 4; ++j) { cs[nf] += acc[mf][nf][j]; cp[nf] += acc[mf][nf][j] * pj[j]; }
    }
  }
#pragma unroll
  for (int off = 16; off < 64; off <<= 1) {
#pragma unroll
    for (int nf = 0; nf < 4; ++nf) { cs[nf] += __shfl_xor(cs[nf], off); cp[nf] += __shfl_xor(cp[nf], off); }
  }
  if (cq == 0) {
#pragma unroll
    for (int nf = 0; nf < 4; ++nf) {
      int col = colbase + wc * 64 + nf * 16 + cn;
      atomicAdd(&accCS[col], cs[nf]);
      atomicAdd(&accCP[col], cp[nf]);
    }
  }
}

// ---------------- pair dot + log-sigmoid (reads precomputed zsum) ----------------
__global__ __launch_bounds__(256) void pair_logsig(const float* __restrict__ ZS1,
                                                   const float* __restrict__ ZS2,
                                                   const int* __restrict__ pi,
                                                   const int* __restrict__ pj,
                                                   const int* __restrict__ ni,
                                                   const int* __restrict__ nj,
                                                   int P, float* __restrict__ lsig) {
  int wid = blockIdx.x * 4 + (threadIdx.x >> 6);
  int lane = threadIdx.x & 63;
  if (wid >= 2 * P) return;
  bool isneg = wid >= P;
  int p = isneg ? wid - P : wid;
  int i = isneg ? ni[p] : pi[p];
  int j = isneg ? nj[p] : pj[p];
  const float4* a = (const float4*)(ZS1 + (size_t)i * HD);
  const float4* b = (const float4*)(ZS2 + (size_t)j * HD);
  float s = 0.f;
#pragma unroll
  for (int t = 0; t < 2; ++t) {
    float4 x = a[lane * 2 + t], y = b[lane * 2 + t];
    s += x.x * y.x + x.y * y.y + x.z * y.z + x.w * y.w;
  }
#pragma unroll
  for (int off = 1; off < 64; off <<= 1) s += __shfl_xor(s, off);
  if (lane == 0) {
    float ip = isneg ? -s : s;
    lsig[wid] = fminf(ip, 0.f) - log1pf(expf(-fabsf(ip)));
  }
}

// ---------------- final reduction + combine ----------------
__global__ __launch_bounds__(256) void finalize(const float* __restrict__ acc,
                                                const float* __restrict__ lsig,
                                                int P, float* __restrict__ out) {
  int tid = threadIdx.x;
  __shared__ float red[256];
  float local[6] = {0.f, 0.f, 0.f, 0.f, 0.f, 0.f};
  for (int l = 0; l < 2; ++l) {
    const float* rs = acc + (size_t)(l * 4 + 0) * NR;
    const float* rp = acc + (size_t)(l * 4 + 1) * NR;
    const float* cs = acc + (size_t)(l * 4 + 2) * NR;
    const float* cp = acc + (size_t)(l * 4 + 3) * NR;
    for (int i = tid; i < NR; i += 256) {
      local[l * 2 + 0] += logf(rp[i] / (rs[i] + 1e-8f));
      local[l * 2 + 1] += logf(cp[i] / (cs[i] + 1e-8f));
    }
  }
  for (int i = tid; i < P; i += 256) local[4] += lsig[i];
  for (int i = tid; i < P; i += 256) local[5] += lsig[P + i];
  float tot[6];
  for (int q = 0; q < 6; ++q) {
    red[tid] = local[q];
    __syncthreads();
    for (int s = 128; s > 0; s >>= 1) {
      if (tid < s) red[tid] += red[tid + s];
      __syncthreads();
    }
    tot[q] = red[0];
    __syncthreads();
  }
  if (tid == 0) {
    float loss1 = LAMBDA * (-tot[0] / (float)NR) + (1.f - LAMBDA) * (-tot[1] / (float)NR);
    float loss2 = LAMBDA * (-tot[2] / (float)NR) + (1.f - LAMBDA) * (-tot[3] / (float)NR);
    float loss_main = -(tot[4] / (float)P) + (tot[5] / (float)P);
    out[0] = loss_main + loss1 + loss2;
  }
}

extern "C" void kernel_launch(void* const* d_in, const int* in_sizes, int n_in,
                              void* d_out, int out_size, void* d_ws, size_t ws_size,
                              hipStream_t stream) {
  const float* z_mp1 = (const float*)d_in[0];
  const float* z_sc1 = (const float*)d_in[1];
  const float* pos1 = (const float*)d_in[2];
  const float* z_mp2 = (const float*)d_in[3];
  const float* z_sc2 = (const float*)d_in[4];
  const float* pos2 = (const float*)d_in[5];
  const float* W1 = (const float*)d_in[6];
  const float* b1 = (const float*)d_in[7];
  const float* W2 = (const float*)d_in[8];
  const float* b2 = (const float*)d_in[9];
  const int* pi = (const int*)d_in[10];
  const int* pj = (const int*)d_in[11];
  const int* ni = (const int*)d_in[12];
  const int* nj = (const int*)d_in[13];
  const int P = in_sizes[10];

  char* ws = (char*)d_ws;
  float* ACC = (float*)(ws);                                   // 16*4096 f32 (zeroed, 8*4096 used)
  float* INV = (float*)(ws + 256 * 1024);                      // 2*4096 f32
  float* LSIG = (float*)(ws + 320 * 1024);                     // 2P f32 (<1.7MB space)
  unsigned short* ZB0 = (unsigned short*)(ws + 2 * 1024 * 1024);   // 4MB
  unsigned short* ZB1 = (unsigned short*)(ws + 6 * 1024 * 1024);   // 4MB
  unsigned short* W1b = (unsigned short*)(ws + 10 * 1024 * 1024);  // 512KB
  unsigned short* W2b = (unsigned short*)(ws + 10 * 1024 * 1024 + 512 * 1024);
  float* ZSUM1 = (float*)(ws + 12 * 1024 * 1024);              // 8MB (reused as HBm/HBs)
  float* ZSUM2 = (float*)(ws + 20 * 1024 * 1024);              // 8MB (reused as PAb/PBb)
  unsigned short* HBm = (unsigned short*)(ws + 12 * 1024 * 1024);
  unsigned short* HBs = (unsigned short*)(ws + 16 * 1024 * 1024);
  unsigned short* PAb = (unsigned short*)(ws + 20 * 1024 * 1024);
  unsigned short* PBb = (unsigned short*)(ws + 24 * 1024 * 1024);

  hipMemsetAsync(ACC, 0, 16 * 4096 * sizeof(float), stream);

  cast_bf16<<<256, 256, 0, stream>>>(W1, W1b, 512 * 512 / 4);
  cast_bf16<<<256, 256, 0, stream>>>(W2, W2b, 512 * 512 / 4);
  addz<<<2048, 256, 0, stream>>>(z_mp1, z_sc1, ZSUM1, NR * HD / 4);
  addz<<<2048, 256, 0, stream>>>(z_mp2, z_sc2, ZSUM2, NR * HD / 4);
  pair_logsig<<<(2 * P + 3) / 4, 256, 0, stream>>>(ZSUM1, ZSUM2, pi, pj, ni, nj, P, LSIG);

  dim3 gP(4, 64);    // proj: N/128 x (2 streams * M/128)
  dim3 gS(32, 32);   // sim: 4096/128 each dim
  for (int ll = 0; ll < 2; ++ll) {
    const float* zm = ll ? z_mp2 : z_mp1;
    const float* zs = ll ? z_sc2 : z_sc1;
    const float* pos = ll ? pos2 : pos1;
    cast_bf16<<<2048, 256, 0, stream>>>(zm, ZB0, NR * HD / 4);
    cast_bf16<<<2048, 256, 0, stream>>>(zs, ZB1, NR * HD / 4);
    proj_mfma<true><<<gP, 256, 0, stream>>>(ZB0, ZB1, W1b, b1, HBm, HBs);
    proj_mfma<false><<<gP, 256, 0, stream>>>(HBm, HBs, W2b, b2, PAb, PBb);
    rownorm_bf<<<1024, 256, 0, stream>>>(PAb, INV, NR);
    rownorm_bf<<<1024, 256, 0, stream>>>(PBb, INV + 4096, NR);
    sim_mfma<<<gS, 256, 0, stream>>>(PAb, PBb, INV, INV + 4096, pos,
                                     ACC + (size_t)(ll * 4 + 0) * 4096, ACC + (size_t)(ll * 4 + 1) * 4096,
                                     ACC + (size_t)(ll * 4 + 2) * 4096, ACC + (size_t)(ll * 4 + 3) * 4096);
  }
  finalize<<<1, 256, 0, stream>>>(ACC, LSIG, P, (float*)d_out);
}

// Round 5
// 492.629 us; speedup vs baseline: 2.6186x; 1.1343x over previous
//
#include <hip/hip_runtime.h>
#include <math.h>

#define TAU_INV 1.25f
#define LAMBDA 0.5f
#define NR 4096
#define HD 512

typedef __attribute__((ext_vector_type(8))) short short8;
typedef __attribute__((ext_vector_type(4))) float f32x4;
typedef __attribute__((ext_vector_type(4))) unsigned short ushort4v;

static __device__ __forceinline__ unsigned short f2bf(float f) {
  unsigned int u = __float_as_uint(f);
  u += 0x7fff + ((u >> 16) & 1);   // RNE
  return (unsigned short)(u >> 16);
}
static __device__ __forceinline__ float bf2f(unsigned short s) {
  return __uint_as_float(((unsigned int)s) << 16);
}

// ---------------- fp32 -> bf16 cast (vectorized) ----------------
__global__ __launch_bounds__(256) void cast_bf16(const float* __restrict__ src,
                                                 unsigned short* __restrict__ dst, int n4) {
  int i = blockIdx.x * 256 + threadIdx.x;
  if (i < n4) {
    float4 v = ((const float4*)src)[i];
    ushort4v o;
    o.x = f2bf(v.x); o.y = f2bf(v.y); o.z = f2bf(v.z); o.w = f2bf(v.w);
    ((ushort4v*)dst)[i] = o;
  }
}

// ---------------- zsum = a + b (fp32, for pair loss) ----------------
__global__ __launch_bounds__(256) void addz(const float* __restrict__ a,
                                            const float* __restrict__ b,
                                            float* __restrict__ o, int n4) {
  int i = blockIdx.x * 256 + threadIdx.x;
  if (i < n4) {
    float4 x = ((const float4*)a)[i], y = ((const float4*)b)[i];
    float4 r; r.x = x.x + y.x; r.y = x.y + y.y; r.z = x.z + y.z; r.w = x.w + y.w;
    ((float4*)o)[i] = r;
  }
}

// ============ MFMA GEMM core macros (128x128 tile, BK=64, XOR-swizzled LDS) ============
// LDS slot (row, c16) holds global element (row, c16 ^ ((row&7)<<4)); reads re-apply the XOR.

#define GEMM_STAGE(Aptr, Bptr, rb, cb_, kb)                                                     \
  {                                                                                             \
    _Pragma("unroll") for (int q = 0; q < 4; ++q) {                                             \
      int r0 = q * 32 + w * 8;                                                                  \
      const char* sa = (const char*)(Aptr) + ((size_t)((rb) + r0 + lrow) << 10) + (kb)*128 + scb;\
      const char* sb = (const char*)(Bptr) + ((size_t)((cb_) + r0 + lrow) << 10) + (kb)*128 + scb;\
      __builtin_amdgcn_global_load_lds((const __attribute__((address_space(1))) unsigned int*)sa,\
          (__attribute__((address_space(3))) unsigned int*)(void*)((char*)As + r0 * 128), 16, 0, 0);\
      __builtin_amdgcn_global_load_lds((const __attribute__((address_space(1))) unsigned int*)sb,\
          (__attribute__((address_space(3))) unsigned int*)(void*)((char*)Bs + r0 * 128), 16, 0, 0);\
    }                                                                                           \
  }

#define GEMM_COMPUTE()                                                                          \
  {                                                                                             \
    _Pragma("unroll") for (int kk = 0; kk < 2; ++kk) {                                          \
      short8 av[4], bv[4];                                                                      \
      _Pragma("unroll") for (int mf = 0; mf < 4; ++mf) {                                        \
        int row = wr * 64 + mf * 16 + (l & 15);                                                 \
        int kbyte = ((kk * 64) + ((l >> 4) * 16)) ^ ((l & 7) << 4);                             \
        av[mf] = *(const short8*)((const char*)As + row * 128 + kbyte);                         \
      }                                                                                        \
      _Pragma("unroll") for (int nf = 0; nf < 4; ++nf) {                                        \
        int row = wc * 64 + nf * 16 + (l & 15);                                                 \
        int kbyte = ((kk * 64) + ((l >> 4) * 16)) ^ ((l & 7) << 4);                             \
        bv[nf] = *(const short8*)((const char*)Bs + row * 128 + kbyte);                         \
      }                                                                                        \
      _Pragma("unroll") for (int mf = 0; mf < 4; ++mf)                                          \
        _Pragma("unroll") for (int nf = 0; nf < 4; ++nf)                                        \
          acc[mf][nf] = __builtin_amdgcn_mfma_f32_16x16x32_bf16(av[mf], bv[nf], acc[mf][nf], 0, 0, 0);\
    }                                                                                           \
  }

// ---------------- proj GEMM: C = A @ W^T + bias (optional ELU), bf16 in/out, 2 streams ----------------
template <bool DO_ELU>
__global__ __launch_bounds__(256) void proj_mfma(const unsigned short* __restrict__ A0,
                                                 const unsigned short* __restrict__ A1,
                                                 const unsigned short* __restrict__ B,
                                                 const float* __restrict__ bias,
                                                 unsigned short* __restrict__ C0,
                                                 unsigned short* __restrict__ C1) {
  __shared__ unsigned short As[128 * 64];
  __shared__ unsigned short Bs[128 * 64];
  const int tid = threadIdx.x;
  const int l = tid & 63, w = tid >> 6;
  const int wr = w >> 1, wc = w & 1;
  const int stream_id = blockIdx.y >> 5;
  const int rowbase = (blockIdx.y & 31) * 128;
  const int colbase = blockIdx.x * 128;
  const unsigned short* A = stream_id ? A1 : A0;
  unsigned short* C = stream_id ? C1 : C0;
  const int lrow = l >> 3;
  const int scb = ((l & 7) ^ lrow) << 4;

  f32x4 acc[4][4];
#pragma unroll
  for (int i = 0; i < 4; ++i)
#pragma unroll
    for (int j = 0; j < 4; ++j) acc[i][j] = (f32x4){0.f, 0.f, 0.f, 0.f};

  for (int kb = 0; kb < 8; ++kb) {
    GEMM_STAGE(A, B, rowbase, colbase, kb);
    __syncthreads();
    GEMM_COMPUTE();
    __syncthreads();
  }

  const int cq = l >> 4, cn = l & 15;
#pragma unroll
  for (int mf = 0; mf < 4; ++mf) {
#pragma unroll
    for (int nf = 0; nf < 4; ++nf) {
      int col = colbase + wc * 64 + nf * 16 + cn;
      float bb = bias[col];
#pragma unroll
      for (int j = 0; j < 4; ++j) {
        int row = rowbase + wr * 64 + mf * 16 + cq * 4 + j;
        float v = acc[mf][nf][j] + bb;
        if (DO_ELU) v = v > 0.f ? v : expm1f(v);
        C[(size_t)row * HD + col] = f2bf(v);
      }
    }
  }
}

// ---------------- row inv-norms from bf16 [rows,512] ----------------
__global__ __launch_bounds__(256) void rownorm_bf(const unsigned short* __restrict__ Z,
                                                  float* __restrict__ inv, int rows) {
  int wid = blockIdx.x * 4 + (threadIdx.x >> 6);
  int lane = threadIdx.x & 63;
  if (wid >= rows) return;
  short8 v = ((const short8*)(Z + (size_t)wid * HD))[lane];
  float s = 0.f;
#pragma unroll
  for (int j = 0; j < 8; ++j) {
    float f = bf2f((unsigned short)v[j]);
    s += f * f;
  }
#pragma unroll
  for (int off = 1; off < 64; off <<= 1) s += __shfl_xor(s, off);
  if (lane == 0) inv[wid] = 1.f / sqrtf(s);
}

// ---------------- fused similarity (MFMA) + exp + row/col pos-weighted reductions ----------------
__global__ __launch_bounds__(256) void sim_mfma(const unsigned short* __restrict__ PA,
                                                const unsigned short* __restrict__ PB,
                                                const float* __restrict__ invA,
                                                const float* __restrict__ invB,
                                                const float* __restrict__ pos,
                                                float* __restrict__ accRS,
                                                float* __restrict__ accRP,
                                                float* __restrict__ accCS,
                                                float* __restrict__ accCP) {
  __shared__ unsigned short As[128 * 64];
  __shared__ unsigned short Bs[128 * 64];
  const int tid = threadIdx.x;
  const int l = tid & 63, w = tid >> 6;
  const int wr = w >> 1, wc = w & 1;
  const int rowbase = blockIdx.y * 128;
  const int colbase = blockIdx.x * 128;
  const int lrow = l >> 3;
  const int scb = ((l & 7) ^ lrow) << 4;

  f32x4 acc[4][4];
#pragma unroll
  for (int i = 0; i < 4; ++i)
#pragma unroll
    for (int j = 0; j < 4; ++j) acc[i][j] = (f32x4){0.f, 0.f, 0.f, 0.f};

  for (int kb = 0; kb < 8; ++kb) {
    GEMM_STAGE(PA, PB, rowbase, colbase, kb);
    __syncthreads();
    GEMM_COMPUTE();
    __syncthreads();
  }

  const int cq = l >> 4, cn = l & 15;
  // scales
  float sr[4][4], sc[4];
#pragma unroll
  for (int mf = 0; mf < 4; ++mf) {
    float4 iv = *(const float4*)(invA + rowbase + wr * 64 + mf * 16 + cq * 4);
    sr[mf][0] = iv.x * TAU_INV; sr[mf][1] = iv.y * TAU_INV;
    sr[mf][2] = iv.z * TAU_INV; sr[mf][3] = iv.w * TAU_INV;
  }
#pragma unroll
  for (int nf = 0; nf < 4; ++nf) sc[nf] = invB[colbase + wc * 64 + nf * 16 + cn];

  // m = exp(dot * invA * invB / tau), in place
#pragma unroll
  for (int mf = 0; mf < 4; ++mf)
#pragma unroll
    for (int nf = 0; nf < 4; ++nf)
#pragma unroll
      for (int j = 0; j < 4; ++j)
        acc[mf][nf][j] = expf(acc[mf][nf][j] * sr[mf][j] * sc[nf]);

  // row sums + pos-weighted row sums
#pragma unroll
  for (int mf = 0; mf < 4; ++mf) {
    float rs[4] = {0.f, 0.f, 0.f, 0.f}, rp[4] = {0.f, 0.f, 0.f, 0.f};
#pragma unroll
    for (int nf = 0; nf < 4; ++nf) {
      int col = colbase + wc * 64 + nf * 16 + cn;
#pragma unroll
      for (int j = 0; j < 4; ++j) {
        float m = acc[mf][nf][j];
        rs[j] += m;
        float p = pos[(size_t)(rowbase + wr * 64 + mf * 16 + cq * 4 + j) * NR + col];
        rp[j] += m * p;
      }
    }
#pragma unroll
    for (int off = 1; off < 16; off <<= 1) {
#pragma unroll
      for (int j = 0; j < 4; ++j) { rs[j] += __shfl_xor(rs[j], off); rp[j] += __shfl_xor(rp[j], off); }
    }
    if (cn == 0) {
#pragma unroll
      for (int j = 0; j < 4; ++j) {
        int row = rowbase + wr * 64 + mf * 16 + cq * 4 + j;
        atomicAdd(&accRS[row], rs[j]);
        atomicAdd(&accRP[row], rp[j]);
      }
    }
  }

  // col sums + pos^T-weighted col sums
  float cs[4] = {0.f, 0.f, 0.f, 0.f}, cp[4] = {0.f, 0.f, 0.f, 0.f};
#pragma unroll
  for (int nf = 0; nf < 4; ++nf) {
    int col = colbase + wc * 64 + nf * 16 + cn;
#pragma unroll
    for (int mf = 0; mf < 4; ++mf) {
      float4 pT = *(const float4*)(pos + (size_t)col * NR + rowbase + wr * 64 + mf * 16 + cq * 4);
      float pj[4] = {pT.x, pT.y, pT.z, pT.w};
#pragma unroll
      for (int j = 0; j < 4; ++j) { cs[nf] += acc[mf][nf][j]; cp[nf] += acc[mf][nf][j] * pj[j]; }
    }
  }
#pragma unroll
  for (int off = 16; off < 64; off <<= 1) {
#pragma unroll
    for (int nf = 0; nf < 4; ++nf) { cs[nf] += __shfl_xor(cs[nf], off); cp[nf] += __shfl_xor(cp[nf], off); }
  }
  if (cq == 0) {
#pragma unroll
    for (int nf = 0; nf < 4; ++nf) {
      int col = colbase + wc * 64 + nf * 16 + cn;
      atomicAdd(&accCS[col], cs[nf]);
      atomicAdd(&accCP[col], cp[nf]);
    }
  }
}

// ---------------- pair dot + log-sigmoid (reads precomputed zsum) ----------------
__global__ __launch_bounds__(256) void pair_logsig(const float* __restrict__ ZS1,
                                                   const float* __restrict__ ZS2,
                                                   const int* __restrict__ pi,
                                                   const int* __restrict__ pj,
                                                   const int* __restrict__ ni,
                                                   const int* __restrict__ nj,
                                                   int P, float* __restrict__ lsig) {
  int wid = blockIdx.x * 4 + (threadIdx.x >> 6);
  int lane = threadIdx.x & 63;
  if (wid >= 2 * P) return;
  bool isneg = wid >= P;
  int p = isneg ? wid - P : wid;
  int i = isneg ? ni[p] : pi[p];
  int j = isneg ? nj[p] : pj[p];
  const float4* a = (const float4*)(ZS1 + (size_t)i * HD);
  const float4* b = (const float4*)(ZS2 + (size_t)j * HD);
  float s = 0.f;
#pragma unroll
  for (int t = 0; t < 2; ++t) {
    float4 x = a[lane * 2 + t], y = b[lane * 2 + t];
    s += x.x * y.x + x.y * y.y + x.z * y.z + x.w * y.w;
  }
#pragma unroll
  for (int off = 1; off < 64; off <<= 1) s += __shfl_xor(s, off);
  if (lane == 0) {
    float ip = isneg ? -s : s;
    lsig[wid] = fminf(ip, 0.f) - log1pf(expf(-fabsf(ip)));
  }
}

// ---------------- parallel partial reduction into TOT[6] ----------------
// TOT layout: {rowlog_l0, collog_l0, rowlog_l1, collog_l1, lsig_pos, lsig_neg}
__global__ __launch_bounds__(256) void reduce_partial(const float* __restrict__ acc,
                                                      const float* __restrict__ lsig,
                                                      int P, float* __restrict__ tot) {
  int gid = blockIdx.x * 256 + threadIdx.x;
  int stride = gridDim.x * 256;
  float loc[6] = {0.f, 0.f, 0.f, 0.f, 0.f, 0.f};
  for (int idx = gid; idx < 2 * NR; idx += stride) {
    int l = idx >> 12, i = idx & (NR - 1);
    const float* base = acc + (size_t)l * 4 * NR;
    float t0 = logf(base[NR + i] / (base[i] + 1e-8f));            // log(rp/rs)
    float t1 = logf(base[3 * NR + i] / (base[2 * NR + i] + 1e-8f)); // log(cp/cs)
    if (l == 0) { loc[0] += t0; loc[1] += t1; }
    else        { loc[2] += t0; loc[3] += t1; }
  }
  for (int i = gid; i < P; i += stride) loc[4] += lsig[i];
  for (int i = gid; i < P; i += stride) loc[5] += lsig[P + i];
#pragma unroll
  for (int q = 0; q < 6; ++q) {
    float s = loc[q];
#pragma unroll
    for (int off = 1; off < 64; off <<= 1) s += __shfl_xor(s, off);
    if ((threadIdx.x & 63) == 0) atomicAdd(&tot[q], s);
  }
}

// ---------------- combine TOT -> scalar ----------------
__global__ void finalize2(const float* __restrict__ tot, int P, float* __restrict__ out) {
  if (threadIdx.x == 0 && blockIdx.x == 0) {
    float loss1 = LAMBDA * (-tot[0] / (float)NR) + (1.f - LAMBDA) * (-tot[1] / (float)NR);
    float loss2 = LAMBDA * (-tot[2] / (float)NR) + (1.f - LAMBDA) * (-tot[3] / (float)NR);
    float loss_main = -(tot[4] / (float)P) + (tot[5] / (float)P);
    out[0] = loss_main + loss1 + loss2;
  }
}

extern "C" void kernel_launch(void* const* d_in, const int* in_sizes, int n_in,
                              void* d_out, int out_size, void* d_ws, size_t ws_size,
                              hipStream_t stream) {
  const float* z_mp1 = (const float*)d_in[0];
  const float* z_sc1 = (const float*)d_in[1];
  const float* pos1 = (const float*)d_in[2];
  const float* z_mp2 = (const float*)d_in[3];
  const float* z_sc2 = (const float*)d_in[4];
  const float* pos2 = (const float*)d_in[5];
  const float* W1 = (const float*)d_in[6];
  const float* b1 = (const float*)d_in[7];
  const float* W2 = (const float*)d_in[8];
  const float* b2 = (const float*)d_in[9];
  const int* pi = (const int*)d_in[10];
  const int* pj = (const int*)d_in[11];
  const int* ni = (const int*)d_in[12];
  const int* nj = (const int*)d_in[13];
  const int P = in_sizes[10];

  char* ws = (char*)d_ws;
  float* ACC = (float*)(ws);                                   // 16*4096 f32 zeroed; [0,8*4096) acc, TOT at 8*4096
  float* TOT = ACC + 8 * 4096;                                 // 6 f32 (inside zeroed region)
  float* INV = (float*)(ws + 256 * 1024);                      // 2*4096 f32
  float* LSIG = (float*)(ws + 320 * 1024);                     // 2P f32 (<1.7MB space)
  unsigned short* ZB0 = (unsigned short*)(ws + 2 * 1024 * 1024);   // 4MB
  unsigned short* ZB1 = (unsigned short*)(ws + 6 * 1024 * 1024);   // 4MB
  unsigned short* W1b = (unsigned short*)(ws + 10 * 1024 * 1024);  // 512KB
  unsigned short* W2b = (unsigned short*)(ws + 10 * 1024 * 1024 + 512 * 1024);
  float* ZSUM1 = (float*)(ws + 12 * 1024 * 1024);              // 8MB (reused as HBm/HBs)
  float* ZSUM2 = (float*)(ws + 20 * 1024 * 1024);              // 8MB (reused as PAb/PBb)
  unsigned short* HBm = (unsigned short*)(ws + 12 * 1024 * 1024);
  unsigned short* HBs = (unsigned short*)(ws + 16 * 1024 * 1024);
  unsigned short* PAb = (unsigned short*)(ws + 20 * 1024 * 1024);
  unsigned short* PBb = (unsigned short*)(ws + 24 * 1024 * 1024);

  hipMemsetAsync(ACC, 0, 16 * 4096 * sizeof(float), stream);

  cast_bf16<<<256, 256, 0, stream>>>(W1, W1b, 512 * 512 / 4);
  cast_bf16<<<256, 256, 0, stream>>>(W2, W2b, 512 * 512 / 4);
  addz<<<2048, 256, 0, stream>>>(z_mp1, z_sc1, ZSUM1, NR * HD / 4);
  addz<<<2048, 256, 0, stream>>>(z_mp2, z_sc2, ZSUM2, NR * HD / 4);
  pair_logsig<<<(2 * P + 3) / 4, 256, 0, stream>>>(ZSUM1, ZSUM2, pi, pj, ni, nj, P, LSIG);

  dim3 gP(4, 64);    // proj: N/128 x (2 streams * M/128)
  dim3 gS(32, 32);   // sim: 4096/128 each dim
  for (int ll = 0; ll < 2; ++ll) {
    const float* zm = ll ? z_mp2 : z_mp1;
    const float* zs = ll ? z_sc2 : z_sc1;
    const float* pos = ll ? pos2 : pos1;
    cast_bf16<<<2048, 256, 0, stream>>>(zm, ZB0, NR * HD / 4);
    cast_bf16<<<2048, 256, 0, stream>>>(zs, ZB1, NR * HD / 4);
    proj_mfma<true><<<gP, 256, 0, stream>>>(ZB0, ZB1, W1b, b1, HBm, HBs);
    proj_mfma<false><<<gP, 256, 0, stream>>>(HBm, HBs, W2b, b2, PAb, PBb);
    rownorm_bf<<<1024, 256, 0, stream>>>(PAb, INV, NR);
    rownorm_bf<<<1024, 256, 0, stream>>>(PBb, INV + 4096, NR);
    sim_mfma<<<gS, 256, 0, stream>>>(PAb, PBb, INV, INV + 4096, pos,
                                     ACC + (size_t)(ll * 4 + 0) * 4096, ACC + (size_t)(ll * 4 + 1) * 4096,
                                     ACC + (size_t)(ll * 4 + 2) * 4096, ACC + (size_t)(ll * 4 + 3) * 4096);
  }
  reduce_partial<<<256, 256, 0, stream>>>(ACC, LSIG, P, TOT);
  finalize2<<<1, 64, 0, stream>>>(TOT, P, (float*)d_out);
}

// Round 6
// 418.193 us; speedup vs baseline: 3.0847x; 1.1780x over previous
//
#include <hip/hip_runtime.h>
#include <math.h>

#define TAU_INV 1.25f
#define LAMBDA 0.5f
#define NR 4096
#define HD 512

typedef __attribute__((ext_vector_type(8))) short short8;
typedef __attribute__((ext_vector_type(4))) float f32x4;
typedef __attribute__((ext_vector_type(4))) unsigned short ushort4v;

static __device__ __forceinline__ unsigned short f2bf(float f) {
  unsigned int u = __float_as_uint(f);
  u += 0x7fff + ((u >> 16) & 1);   // RNE
  return (unsigned short)(u >> 16);
}
static __device__ __forceinline__ float bf2f(unsigned short s) {
  return __uint_as_float(((unsigned int)s) << 16);
}

// ---------------- fp32 -> bf16 cast (vectorized) ----------------
__global__ __launch_bounds__(256) void cast_bf16(const float* __restrict__ src,
                                                 unsigned short* __restrict__ dst, int n4) {
  int i = blockIdx.x * 256 + threadIdx.x;
  if (i < n4) {
    float4 v = ((const float4*)src)[i];
    ushort4v o;
    o.x = f2bf(v.x); o.y = f2bf(v.y); o.z = f2bf(v.z); o.w = f2bf(v.w);
    ((ushort4v*)dst)[i] = o;
  }
}

// ---------------- zsum = a + b (fp32, for pair loss) ----------------
__global__ __launch_bounds__(256) void addz(const float* __restrict__ a,
                                            const float* __restrict__ b,
                                            float* __restrict__ o, int n4) {
  int i = blockIdx.x * 256 + threadIdx.x;
  if (i < n4) {
    float4 x = ((const float4*)a)[i], y = ((const float4*)b)[i];
    float4 r; r.x = x.x + y.x; r.y = x.y + y.y; r.z = x.z + y.z; r.w = x.w + y.w;
    ((float4*)o)[i] = r;
  }
}

// ============ MFMA GEMM core macros (128x128 tile, BK=64, XOR-swizzled LDS) ============
// LDS slot (row, c16) holds global element (row, c16 ^ ((row&7)<<4)); reads re-apply the XOR.

#define GEMM_STAGE(Aptr, Bptr, rb, cb_, kb)                                                     \
  {                                                                                             \
    _Pragma("unroll") for (int q = 0; q < 4; ++q) {                                             \
      int r0 = q * 32 + w * 8;                                                                  \
      const char* sa = (const char*)(Aptr) + ((size_t)((rb) + r0 + lrow) << 10) + (kb)*128 + scb;\
      const char* sb = (const char*)(Bptr) + ((size_t)((cb_) + r0 + lrow) << 10) + (kb)*128 + scb;\
      __builtin_amdgcn_global_load_lds((const __attribute__((address_space(1))) unsigned int*)sa,\
          (__attribute__((address_space(3))) unsigned int*)(void*)((char*)As + r0 * 128), 16, 0, 0);\
      __builtin_amdgcn_global_load_lds((const __attribute__((address_space(1))) unsigned int*)sb,\
          (__attribute__((address_space(3))) unsigned int*)(void*)((char*)Bs + r0 * 128), 16, 0, 0);\
    }                                                                                           \
  }

#define GEMM_COMPUTE()                                                                          \
  {                                                                                             \
    _Pragma("unroll") for (int kk = 0; kk < 2; ++kk) {                                          \
      short8 av[4], bv[4];                                                                      \
      _Pragma("unroll") for (int mf = 0; mf < 4; ++mf) {                                        \
        int row = wr * 64 + mf * 16 + (l & 15);                                                 \
        int kbyte = ((kk * 64) + ((l >> 4) * 16)) ^ ((l & 7) << 4);                             \
        av[mf] = *(const short8*)((const char*)As + row * 128 + kbyte);                         \
      }                                                                                        \
      _Pragma("unroll") for (int nf = 0; nf < 4; ++nf) {                                        \
        int row = wc * 64 + nf * 16 + (l & 15);                                                 \
        int kbyte = ((kk * 64) + ((l >> 4) * 16)) ^ ((l & 7) << 4);                             \
        bv[nf] = *(const short8*)((const char*)Bs + row * 128 + kbyte);                         \
      }                                                                                        \
      _Pragma("unroll") for (int mf = 0; mf < 4; ++mf)                                          \
        _Pragma("unroll") for (int nf = 0; nf < 4; ++nf)                                        \
          acc[mf][nf] = __builtin_amdgcn_mfma_f32_16x16x32_bf16(av[mf], bv[nf], acc[mf][nf], 0, 0, 0);\
    }                                                                                           \
  }

// ---------------- proj GEMM: C = A @ W^T + bias (optional ELU), bf16 in/out, 2 streams ----------------
template <bool DO_ELU>
__global__ __launch_bounds__(256) void proj_mfma(const unsigned short* __restrict__ A0,
                                                 const unsigned short* __restrict__ A1,
                                                 const unsigned short* __restrict__ B,
                                                 const float* __restrict__ bias,
                                                 unsigned short* __restrict__ C0,
                                                 unsigned short* __restrict__ C1) {
  __shared__ unsigned short As[128 * 64];
  __shared__ unsigned short Bs[128 * 64];
  const int tid = threadIdx.x;
  const int l = tid & 63, w = tid >> 6;
  const int wr = w >> 1, wc = w & 1;
  const int stream_id = blockIdx.y >> 5;
  const int rowbase = (blockIdx.y & 31) * 128;
  const int colbase = blockIdx.x * 128;
  const unsigned short* A = stream_id ? A1 : A0;
  unsigned short* C = stream_id ? C1 : C0;
  const int lrow = l >> 3;
  const int scb = ((l & 7) ^ lrow) << 4;

  f32x4 acc[4][4];
#pragma unroll
  for (int i = 0; i < 4; ++i)
#pragma unroll
    for (int j = 0; j < 4; ++j) acc[i][j] = (f32x4){0.f, 0.f, 0.f, 0.f};

  for (int kb = 0; kb < 8; ++kb) {
    GEMM_STAGE(A, B, rowbase, colbase, kb);
    __syncthreads();
    GEMM_COMPUTE();
    __syncthreads();
  }

  const int cq = l >> 4, cn = l & 15;
#pragma unroll
  for (int mf = 0; mf < 4; ++mf) {
#pragma unroll
    for (int nf = 0; nf < 4; ++nf) {
      int col = colbase + wc * 64 + nf * 16 + cn;
      float bb = bias[col];
#pragma unroll
      for (int j = 0; j < 4; ++j) {
        int row = rowbase + wr * 64 + mf * 16 + cq * 4 + j;
        float v = acc[mf][nf][j] + bb;
        if (DO_ELU) v = v > 0.f ? v : expm1f(v);
        C[(size_t)row * HD + col] = f2bf(v);
      }
    }
  }
}

// ---------------- row inv-norms from bf16 [rows,512] ----------------
__global__ __launch_bounds__(256) void rownorm_bf(const unsigned short* __restrict__ Z,
                                                  float* __restrict__ inv, int rows) {
  int wid = blockIdx.x * 4 + (threadIdx.x >> 6);
  int lane = threadIdx.x & 63;
  if (wid >= rows) return;
  short8 v = ((const short8*)(Z + (size_t)wid * HD))[lane];
  float s = 0.f;
#pragma unroll
  for (int j = 0; j < 8; ++j) {
    float f = bf2f((unsigned short)v[j]);
    s += f * f;
  }
#pragma unroll
  for (int off = 1; off < 64; off <<= 1) s += __shfl_xor(s, off);
  if (lane == 0) inv[wid] = 1.f / sqrtf(s);
}

// ---------------- fused similarity (MFMA) + exp + row/col pos-weighted reductions ----------------
__global__ __launch_bounds__(256) void sim_mfma(const unsigned short* __restrict__ PA,
                                                const unsigned short* __restrict__ PB,
                                                const float* __restrict__ invA,
                                                const float* __restrict__ invB,
                                                const float* __restrict__ pos,
                                                float* __restrict__ accRS,
                                                float* __restrict__ accRP,
                                                float* __restrict__ accCS,
                                                float* __restrict__ accCP) {
  __shared__ unsigned short As[128 * 64];
  __shared__ unsigned short Bs[128 * 64];
  const int tid = threadIdx.x;
  const int l = tid & 63, w = tid >> 6;
  const int wr = w >> 1, wc = w & 1;
  const int rowbase = blockIdx.y * 128;
  const int colbase = blockIdx.x * 128;
  const int lrow = l >> 3;
  const int scb = ((l & 7) ^ lrow) << 4;

  f32x4 acc[4][4];
#pragma unroll
  for (int i = 0; i < 4; ++i)
#pragma unroll
    for (int j = 0; j < 4; ++j) acc[i][j] = (f32x4){0.f, 0.f, 0.f, 0.f};

  for (int kb = 0; kb < 8; ++kb) {
    GEMM_STAGE(PA, PB, rowbase, colbase, kb);
    __syncthreads();
    GEMM_COMPUTE();
    __syncthreads();
  }

  const int cq = l >> 4, cn = l & 15;
  // scales
  float sr[4][4], sc[4];
#pragma unroll
  for (int mf = 0; mf < 4; ++mf) {
    float4 iv = *(const float4*)(invA + rowbase + wr * 64 + mf * 16 + cq * 4);
    sr[mf][0] = iv.x * TAU_INV; sr[mf][1] = iv.y * TAU_INV;
    sr[mf][2] = iv.z * TAU_INV; sr[mf][3] = iv.w * TAU_INV;
  }
#pragma unroll
  for (int nf = 0; nf < 4; ++nf) sc[nf] = invB[colbase + wc * 64 + nf * 16 + cn];

  // m = exp(dot * invA * invB / tau), in place
#pragma unroll
  for (int mf = 0; mf < 4; ++mf)
#pragma unroll
    for (int nf = 0; nf < 4; ++nf)
#pragma unroll
      for (int j = 0; j < 4; ++j)
        acc[mf][nf][j] = expf(acc[mf][nf][j] * sr[mf][j] * sc[nf]);

  // row sums + pos-weighted row sums
#pragma unroll
  for (int mf = 0; mf < 4; ++mf) {
    float rs[4] = {0.f, 0.f, 0.f, 0.f}, rp[4] = {0.f, 0.f, 0.f, 0.f};
#pragma unroll
    for (int nf = 0; nf < 4; ++nf) {
      int col = colbase + wc * 64 + nf * 16 + cn;
#pragma unroll
      for (int j = 0; j < 4; ++j) {
        float m = acc[mf][nf][j];
        rs[j] += m;
        float p = pos[(size_t)(rowbase + wr * 64 + mf * 16 + cq * 4 + j) * NR + col];
        rp[j] += m * p;
      }
    }
#pragma unroll
    for (int off = 1; off < 16; off <<= 1) {
#pragma unroll
      for (int j = 0; j < 4; ++j) { rs[j] += __shfl_xor(rs[j], off); rp[j] += __shfl_xor(rp[j], off); }
    }
    if (cn == 0) {
#pragma unroll
      for (int j = 0; j < 4; ++j) {
        int row = rowbase + wr * 64 + mf * 16 + cq * 4 + j;
        atomicAdd(&accRS[row], rs[j]);
        atomicAdd(&accRP[row], rp[j]);
      }
    }
  }

  // col sums + pos^T-weighted col sums
  float cs[4] = {0.f, 0.f, 0.f, 0.f}, cp[4] = {0.f, 0.f, 0.f, 0.f};
#pragma unroll
  for (int nf = 0; nf < 4; ++nf) {
    int col = colbase + wc * 64 + nf * 16 + cn;
#pragma unroll
    for (int mf = 0; mf < 4; ++mf) {
      float4 pT = *(const float4*)(pos + (size_t)col * NR + rowbase + wr * 64 + mf * 16 + cq * 4);
      float pj[4] = {pT.x, pT.y, pT.z, pT.w};
#pragma unroll
      for (int j = 0; j < 4; ++j) { cs[nf] += acc[mf][nf][j]; cp[nf] += acc[mf][nf][j] * pj[j]; }
    }
  }
#pragma unroll
  for (int off = 16; off < 64; off <<= 1) {
#pragma unroll
    for (int nf = 0; nf < 4; ++nf) { cs[nf] += __shfl_xor(cs[nf], off); cp[nf] += __shfl_xor(cp[nf], off); }
  }
  if (cq == 0) {
#pragma unroll
    for (int nf = 0; nf < 4; ++nf) {
      int col = colbase + wc * 64 + nf * 16 + cn;
      atomicAdd(&accCS[col], cs[nf]);
      atomicAdd(&accCP[col], cp[nf]);
    }
  }
}

// ---------------- pair dot + log-sigmoid (reads precomputed zsum) ----------------
__global__ __launch_bounds__(256) void pair_logsig(const float* __restrict__ ZS1,
                                                   const float* __restrict__ ZS2,
                                                   const int* __restrict__ pi,
                                                   const int* __restrict__ pj,
                                                   const int* __restrict__ ni,
                                                   const int* __restrict__ nj,
                                                   int P, float* __restrict__ lsig) {
  int wid = blockIdx.x * 4 + (threadIdx.x >> 6);
  int lane = threadIdx.x & 63;
  if (wid >= 2 * P) return;
  bool isneg = wid >= P;
  int p = isneg ? wid - P : wid;
  int i = isneg ? ni[p] : pi[p];
  int j = isneg ? nj[p] : pj[p];
  const float4* a = (const float4*)(ZS1 + (size_t)i * HD);
  const float4* b = (const float4*)(ZS2 + (size_t)j * HD);
  float s = 0.f;
#pragma unroll
  for (int t = 0; t < 2; ++t) {
    float4 x = a[lane * 2 + t], y = b[lane * 2 + t];
    s += x.x * y.x + x.y * y.y + x.z * y.z + x.w * y.w;
  }
#pragma unroll
  for (int off = 1; off < 64; off <<= 1) s += __shfl_xor(s, off);
  if (lane == 0) {
    float ip = isneg ? -s : s;
    lsig[wid] = fminf(ip, 0.f) - log1pf(expf(-fabsf(ip)));
  }
}

// ---------------- parallel partial reduction -> per-block partials (NO contended atomics) ----------------
// part[blk*6 + q], q: {rowlog_l0, collog_l0, rowlog_l1, collog_l1, lsig_pos, lsig_neg}
#define RED_BLOCKS 128
__global__ __launch_bounds__(256) void reduce_partial(const float* __restrict__ acc,
                                                      const float* __restrict__ lsig,
                                                      int P, float* __restrict__ part) {
  __shared__ float red[6][4];
  int tid = threadIdx.x;
  int gid = blockIdx.x * 256 + tid;
  int stride = gridDim.x * 256;
  float loc[6] = {0.f, 0.f, 0.f, 0.f, 0.f, 0.f};
  for (int idx = gid; idx < 2 * NR; idx += stride) {
    int l = idx >> 12, i = idx & (NR - 1);
    const float* base = acc + (size_t)l * 4 * NR;
    float t0 = logf(base[NR + i] / (base[i] + 1e-8f));              // log(rp/rs)
    float t1 = logf(base[3 * NR + i] / (base[2 * NR + i] + 1e-8f)); // log(cp/cs)
    if (l == 0) { loc[0] += t0; loc[1] += t1; }
    else        { loc[2] += t0; loc[3] += t1; }
  }
  for (int i = gid; i < P; i += stride) loc[4] += lsig[i];
  for (int i = gid; i < P; i += stride) loc[5] += lsig[P + i];
  int wv = tid >> 6, ln = tid & 63;
#pragma unroll
  for (int q = 0; q < 6; ++q) {
    float s = loc[q];
#pragma unroll
    for (int off = 1; off < 64; off <<= 1) s += __shfl_xor(s, off);
    if (ln == 0) red[q][wv] = s;
  }
  __syncthreads();
  if (tid < 6) part[blockIdx.x * 6 + tid] = red[tid][0] + red[tid][1] + red[tid][2] + red[tid][3];
}

// ---------------- combine partials -> scalar (1 wave) ----------------
__global__ __launch_bounds__(64) void finalize2(const float* __restrict__ part,
                                                int P, float* __restrict__ out) {
  int ln = threadIdx.x;  // 0..63
  float t[6];
#pragma unroll
  for (int q = 0; q < 6; ++q) {
    float s = part[ln * 6 + q] + part[(ln + 64) * 6 + q];
#pragma unroll
    for (int off = 1; off < 64; off <<= 1) s += __shfl_xor(s, off);
    t[q] = s;
  }
  if (ln == 0) {
    float loss1 = LAMBDA * (-t[0] / (float)NR) + (1.f - LAMBDA) * (-t[1] / (float)NR);
    float loss2 = LAMBDA * (-t[2] / (float)NR) + (1.f - LAMBDA) * (-t[3] / (float)NR);
    float loss_main = -(t[4] / (float)P) + (t[5] / (float)P);
    out[0] = loss_main + loss1 + loss2;
  }
}

extern "C" void kernel_launch(void* const* d_in, const int* in_sizes, int n_in,
                              void* d_out, int out_size, void* d_ws, size_t ws_size,
                              hipStream_t stream) {
  const float* z_mp1 = (const float*)d_in[0];
  const float* z_sc1 = (const float*)d_in[1];
  const float* pos1 = (const float*)d_in[2];
  const float* z_mp2 = (const float*)d_in[3];
  const float* z_sc2 = (const float*)d_in[4];
  const float* pos2 = (const float*)d_in[5];
  const float* W1 = (const float*)d_in[6];
  const float* b1 = (const float*)d_in[7];
  const float* W2 = (const float*)d_in[8];
  const float* b2 = (const float*)d_in[9];
  const int* pi = (const int*)d_in[10];
  const int* pj = (const int*)d_in[11];
  const int* ni = (const int*)d_in[12];
  const int* nj = (const int*)d_in[13];
  const int P = in_sizes[10];

  char* ws = (char*)d_ws;
  float* ACC = (float*)(ws);                                   // 16*4096 f32 zeroed; [0,8*4096) acc
  float* PART = ACC + 8 * 4096;                                // 128*6 f32 (fully overwritten)
  float* INV = (float*)(ws + 256 * 1024);                      // 2*4096 f32
  float* LSIG = (float*)(ws + 320 * 1024);                     // 2P f32 (<1.7MB space)
  unsigned short* ZB0 = (unsigned short*)(ws + 2 * 1024 * 1024);   // 4MB
  unsigned short* ZB1 = (unsigned short*)(ws + 6 * 1024 * 1024);   // 4MB
  unsigned short* W1b = (unsigned short*)(ws + 10 * 1024 * 1024);  // 512KB
  unsigned short* W2b = (unsigned short*)(ws + 10 * 1024 * 1024 + 512 * 1024);
  float* ZSUM1 = (float*)(ws + 12 * 1024 * 1024);              // 8MB (reused as HBm/HBs)
  float* ZSUM2 = (float*)(ws + 20 * 1024 * 1024);              // 8MB (reused as PAb/PBb)
  unsigned short* HBm = (unsigned short*)(ws + 12 * 1024 * 1024);
  unsigned short* HBs = (unsigned short*)(ws + 16 * 1024 * 1024);
  unsigned short* PAb = (unsigned short*)(ws + 20 * 1024 * 1024);
  unsigned short* PBb = (unsigned short*)(ws + 24 * 1024 * 1024);

  hipMemsetAsync(ACC, 0, 16 * 4096 * sizeof(float), stream);

  cast_bf16<<<256, 256, 0, stream>>>(W1, W1b, 512 * 512 / 4);
  cast_bf16<<<256, 256, 0, stream>>>(W2, W2b, 512 * 512 / 4);
  addz<<<2048, 256, 0, stream>>>(z_mp1, z_sc1, ZSUM1, NR * HD / 4);
  addz<<<2048, 256, 0, stream>>>(z_mp2, z_sc2, ZSUM2, NR * HD / 4);
  pair_logsig<<<(2 * P + 3) / 4, 256, 0, stream>>>(ZSUM1, ZSUM2, pi, pj, ni, nj, P, LSIG);

  dim3 gP(4, 64);    // proj: N/128 x (2 streams * M/128)
  dim3 gS(32, 32);   // sim: 4096/128 each dim
  for (int ll = 0; ll < 2; ++ll) {
    const float* zm = ll ? z_mp2 : z_mp1;
    const float* zs = ll ? z_sc2 : z_sc1;
    const float* pos = ll ? pos2 : pos1;
    cast_bf16<<<2048, 256, 0, stream>>>(zm, ZB0, NR * HD / 4);
    cast_bf16<<<2048, 256, 0, stream>>>(zs, ZB1, NR * HD / 4);
    proj_mfma<true><<<gP, 256, 0, stream>>>(ZB0, ZB1, W1b, b1, HBm, HBs);
    proj_mfma<false><<<gP, 256, 0, stream>>>(HBm, HBs, W2b, b2, PAb, PBb);
    rownorm_bf<<<1024, 256, 0, stream>>>(PAb, INV, NR);
    rownorm_bf<<<1024, 256, 0, stream>>>(PBb, INV + 4096, NR);
    sim_mfma<<<gS, 256, 0, stream>>>(PAb, PBb, INV, INV + 4096, pos,
                                     ACC + (size_t)(ll * 4 + 0) * 4096, ACC + (size_t)(ll * 4 + 1) * 4096,
                                     ACC + (size_t)(ll * 4 + 2) * 4096, ACC + (size_t)(ll * 4 + 3) * 4096);
  }
  reduce_partial<<<RED_BLOCKS, 256, 0, stream>>>(ACC, LSIG, P, PART);
  finalize2<<<1, 64, 0, stream>>>(PART, P, (float*)d_out);
}